// Round 5
// baseline (84.765 us; speedup 1.0000x reference)
//
#include <hip/hip_runtime.h>
#include <math.h>

#define B_    2
#define S_    512
#define HDIM  1024
#define D_    24      // proj dim
#define M_    96      // pair-MLP hidden
#define ROWS  (B_*S_) // 1024

typedef _Float16 half8 __attribute__((ext_vector_type(8)));
typedef float    f32x4 __attribute__((ext_vector_type(4)));
typedef unsigned short ushort8 __attribute__((ext_vector_type(8)));

// ---------------------------------------------------------------------------
// 64x64 fp32->fp16 transpose tile through fp16 LDS (stride-72 rows)
// in[R][C] tile at (R0,C0) -> out[C][R]
// ---------------------------------------------------------------------------
__device__ __forceinline__ void transpose_tile64(
    const float* __restrict__ in, _Float16* __restrict__ out,
    int R, int C, int xt, int yt, _Float16* tileh, int t) {
  int R0 = yt * 64, C0 = xt * 64;
  {
    int r = t >> 4, c4 = (t & 15) * 4;
#pragma unroll
    for (int i = 0; i < 4; ++i) {
      float4 v = *(const float4*)(in + (size_t)(R0 + r + i * 16) * C + C0 + c4);
      _Float16 o[4] = {(_Float16)v.x, (_Float16)v.y, (_Float16)v.z, (_Float16)v.w};
      *(ushort4*)(tileh + (r + i * 16) * 72 + c4) = *(ushort4*)o;
    }
  }
  __syncthreads();
  {
    int r0 = (t & 7) * 8;
#pragma unroll
    for (int p = 0; p < 2; ++p) {
      int c = p * 32 + (t >> 3);
      _Float16 o[8];
#pragma unroll
      for (int e = 0; e < 8; ++e) o[e] = tileh[(r0 + e) * 72 + c];
      *(ushort8*)(out + (size_t)(C0 + c) * R + R0 + r0) = *(ushort8*)o;
    }
  }
}

// ---------------------------------------------------------------------------
// row projection: acc[24] += h[k]*P[k][d] for this thread's 4 k's, then
// wave shfl-reduce + LDS cross-wave; writes Z[r][0..23]
// ---------------------------------------------------------------------------
__device__ __forceinline__ void proj_row(
    float4 h, const float* __restrict__ P, float* __restrict__ Zrow,
    float* red4, int t) {
  float acc[D_];
#pragma unroll
  for (int d = 0; d < D_; ++d) acc[d] = 0.f;
  const float* hh = (const float*)&h;
#pragma unroll
  for (int kk = 0; kk < 4; ++kk) {
    const float4* p4 = (const float4*)(P + (size_t)(t * 4 + kk) * D_);
    float a = hh[kk];
#pragma unroll
    for (int q = 0; q < 6; ++q) {
      float4 w = p4[q];
      acc[q * 4 + 0] = fmaf(a, w.x, acc[q * 4 + 0]);
      acc[q * 4 + 1] = fmaf(a, w.y, acc[q * 4 + 1]);
      acc[q * 4 + 2] = fmaf(a, w.z, acc[q * 4 + 2]);
      acc[q * 4 + 3] = fmaf(a, w.w, acc[q * 4 + 3]);
    }
  }
  int w = t >> 6, l = t & 63;
#pragma unroll
  for (int d = 0; d < D_; ++d) {
#pragma unroll
    for (int off = 32; off > 0; off >>= 1) acc[d] += __shfl_xor(acc[d], off);
  }
  if (l == 0) {
#pragma unroll
    for (int d = 0; d < D_; ++d) red4[w * D_ + d] = acc[d];
  }
  __syncthreads();
  if (t < D_)
    Zrow[t] = red4[t] + red4[D_ + t] + red4[2 * D_ + t] + red4[3 * D_ + t];
}

// ---------------------------------------------------------------------------
// Merged prep kernel: blockIdx ranges
//  [0,4)        : Wimg (fp16 subtiled image of W1 rows 24..95 + zero pad)
//  [4,1028)     : HjH convert row + Zj proj (row = bid-4)
//  [1028,2052)  : Zi proj (row = bid-1028)
//  [2052,2308)  : HiT 64x64 tiles (128 per batch)
//  [2308,2820)  : Wv1T tiles
//  [2820,3076)  : Wv2T tiles
// ---------------------------------------------------------------------------
__global__ __launch_bounds__(256) void prep_kernel(
    const float* __restrict__ Hj, const float* __restrict__ Hi,
    const float* __restrict__ pj, const float* __restrict__ pi,
    const float* __restrict__ W1, const float* __restrict__ Wv1,
    const float* __restrict__ Wv2,
    _Float16* __restrict__ HjH, _Float16* __restrict__ HiT,
    _Float16* __restrict__ Wv1T, _Float16* __restrict__ Wv2T,
    _Float16* __restrict__ Wimg, float* __restrict__ Zj,
    float* __restrict__ Zi) {
  __shared__ __attribute__((aligned(16))) _Float16 tileh[64 * 72];
  const int bid = blockIdx.x;
  const int t = threadIdx.x;

  if (bid < 4) {
    int c = bid * 256 + t;   // 0..1023
    half8 v = {};
    if (c < 864) {
      int kc = c / 96, m = c - kc * 96;
#pragma unroll
      for (int e = 0; e < 8; ++e)
        v[e] = (_Float16)W1[(24 + kc * 8 + e) * M_ + m];
    }
    *(half8*)(Wimg + (size_t)c * 8) = v;
  } else if (bid < 1028) {
    int r = bid - 4;
    float4 h = ((const float4*)(Hj + (size_t)r * HDIM))[t];
    _Float16 o[4] = {(_Float16)h.x, (_Float16)h.y, (_Float16)h.z, (_Float16)h.w};
    ((ushort4*)HjH)[(size_t)r * 256 + t] = *(ushort4*)o;
    proj_row(h, pj, Zj + (size_t)r * D_, (float*)tileh, t);
  } else if (bid < 2052) {
    int r = bid - 1028;
    float4 h = ((const float4*)(Hi + (size_t)r * HDIM))[t];
    proj_row(h, pi, Zi + (size_t)r * D_, (float*)tileh, t);
  } else if (bid < 2308) {
    int id = bid - 2052;
    int z = id >> 7, rem = id & 127;   // 16 x 8 tiles per batch
    transpose_tile64(Hi + (size_t)z * S_ * HDIM, HiT + (size_t)z * HDIM * S_,
                     S_, HDIM, rem & 15, rem >> 4, tileh, t);
  } else if (bid < 2820) {
    int id = bid - 2308;               // 16 x 32 tiles
    transpose_tile64(Wv1, Wv1T, 2 * HDIM, HDIM, id & 15, id >> 4, tileh, t);
  } else {
    int id = bid - 2820;               // 16 x 16 tiles
    transpose_tile64(Wv2, Wv2T, HDIM, HDIM, id & 15, id >> 4, tileh, t);
  }
}

// ---------------------------------------------------------------------------
// Fused pair-MLP + softmax. One block per j-row (1024 blocks, 256 thr).
// C = Wbig(M=96h) x F(N=keys): relu.W2 reduce = 24 in-lane FMAs + 2 shfl.
// ---------------------------------------------------------------------------
#define FOFFB   0                       // 10*256*16 = 40960
#define WOFFB   40960                   // 1024 chunks * 16 = 16384
#define ZOFFB   (WOFFB + 960*16)        // zero chunk
#define LOGOFFB (WOFFB + 16384)         // 512 f32 logits
#define ZJOFFB  (LOGOFFB + 2048)        // 24 f32
#define W2OFFB  (ZJOFFB + 96)           // 96 f32
#define REDOFFB (W2OFFB + 384)          // 8 f32
#define LDSB    (REDOFFB + 32)

__global__ __launch_bounds__(256) void pair_fused_kernel(
    const float* __restrict__ Zj, const float* __restrict__ Zi,
    const float* __restrict__ W1, const float* __restrict__ b1,
    const float* __restrict__ W2, const _Float16* __restrict__ Wimg,
    const float* __restrict__ mask, _Float16* __restrict__ probs) {
  __shared__ __attribute__((aligned(16))) char smem[LDSB];
  const int t = threadIdx.x;
  const int w = t >> 6, l = t & 63;
  const int lo = l & 15, hi = l >> 4;
  const int rj = blockIdx.x;
  const int b = rj >> 9;

  // stage weight image -> LDS (wave-linear dest)
#pragma unroll
  for (int r = 0; r < 4; ++r) {
    const _Float16* src = Wimg + (size_t)(r * 256 + w * 64 + l) * 8;
    __builtin_amdgcn_global_load_lds(
        (const __attribute__((address_space(1))) void*)src,
        (__attribute__((address_space(3))) void*)(smem + WOFFB + (r * 256 + w * 64) * 16),
        16, 0, 0);
  }
  float* zjL    = (float*)(smem + ZJOFFB);
  float* W2s    = (float*)(smem + W2OFFB);
  float* logits = (float*)(smem + LOGOFFB);
  float* red    = (float*)(smem + REDOFFB);
  if (t < D_) zjL[t] = Zj[(size_t)rj * D_ + t];
  if (t < M_) W2s[t] = W2[t];
  float aj = 0.f;
  if (t < M_) {
    aj = b1[t];
#pragma unroll
    for (int d = 0; d < D_; ++d)
      aj = fmaf(Zj[(size_t)rj * D_ + d], W1[d * M_ + t], aj);
  }
  __syncthreads();   // staging + zjL/W2s visible
  if (t < M_) {
    half8 v = {};
    v[0] = (_Float16)aj;
    *(half8*)(smem + WOFFB + (864 + t) * 16) = v;  // Aj row at K=72
  }

  half8 wf[6][3];
  float w2r[6][4];

  for (int p = 0; p < 2; ++p) {
    // ---- feature build: thread owns key i = p*256 + t ----
    {
      int i = p * 256 + t;
      const float* zi = Zi + (size_t)(b * S_ + i) * D_;
      float ziv[D_];
#pragma unroll
      for (int q = 0; q < 6; ++q) {
        float4 v = ((const float4*)zi)[q];
        ziv[q * 4 + 0] = v.x; ziv[q * 4 + 1] = v.y;
        ziv[q * 4 + 2] = v.z; ziv[q * 4 + 3] = v.w;
      }
#pragma unroll
      for (int kc = 0; kc < 3; ++kc) {
        half8 v;
#pragma unroll
        for (int e = 0; e < 8; ++e) v[e] = (_Float16)ziv[kc * 8 + e];
        *(half8*)(smem + FOFFB + (kc * 256 + t) * 16) = v;
      }
#pragma unroll
      for (int kc = 0; kc < 3; ++kc) {
        half8 v;
#pragma unroll
        for (int e = 0; e < 8; ++e) {
          int d = kc * 8 + e;
          v[e] = (_Float16)(zjL[d] * ziv[d]);
        }
        *(half8*)(smem + FOFFB + ((kc + 3) * 256 + t) * 16) = v;
      }
#pragma unroll
      for (int kc = 0; kc < 3; ++kc) {
        half8 v;
#pragma unroll
        for (int e = 0; e < 8; ++e) {
          int d = kc * 8 + e;
          v[e] = (_Float16)fabsf(zjL[d] - ziv[d]);
        }
        *(half8*)(smem + FOFFB + ((kc + 6) * 256 + t) * 16) = v;
      }
      if (p == 0) {
        half8 v = {};
        v[0] = (_Float16)1.0f;
        *(half8*)(smem + FOFFB + (9 * 256 + t) * 16) = v;
      }
    }
    __syncthreads();

    if (p == 0) {   // cache W fragments + W2 slice in regs (const across passes)
#pragma unroll
      for (int mh = 0; mh < 6; ++mh) {
#pragma unroll
        for (int ks = 0; ks < 3; ++ks) {
          int kc = ks * 4 + hi;
          int off = (kc < 10) ? (WOFFB + (kc * 96 + mh * 16 + lo) * 16) : ZOFFB;
          wf[mh][ks] = *(const half8*)(smem + off);
        }
#pragma unroll
        for (int r = 0; r < 4; ++r) w2r[mh][r] = W2s[mh * 16 + hi * 4 + r];
      }
    }

    // ---- MFMA: wave w owns keys w*64 .. w*64+63 (4 N-tiles) ----
#pragma unroll
    for (int nt = 0; nt < 4; ++nt) {
      half8 ff[3];
#pragma unroll
      for (int ks = 0; ks < 3; ++ks) {
        int kc = ks * 4 + hi;
        int off = (kc < 10) ? (FOFFB + (kc * 256 + w * 64 + nt * 16 + lo) * 16) : ZOFFB;
        ff[ks] = *(const half8*)(smem + off);
      }
      f32x4 a6[6] = {};
      __builtin_amdgcn_s_setprio(1);
#pragma unroll
      for (int ks = 0; ks < 3; ++ks)
#pragma unroll
        for (int mh = 0; mh < 6; ++mh)
          a6[mh] = __builtin_amdgcn_mfma_f32_16x16x32_f16(wf[mh][ks], ff[ks], a6[mh], 0, 0, 0);
      __builtin_amdgcn_s_setprio(0);
      float part = 0.f;
#pragma unroll
      for (int mh = 0; mh < 6; ++mh)
#pragma unroll
        for (int r = 0; r < 4; ++r)
          part = fmaf(fmaxf(a6[mh][r], 0.f), w2r[mh][r], part);
      part += __shfl_xor(part, 16);
      part += __shfl_xor(part, 32);
      if (hi == 0) logits[p * 256 + w * 64 + nt * 16 + lo] = part;
    }
    __syncthreads();
  }

  // ---- masked softmax over 512 keys (b2 dropped: shift-invariant) ----
  float m1 = mask[b * S_ + t], m2 = mask[b * S_ + t + 256];
  float lg1 = logits[t]       + (1.0f - m1) * (-3.40282347e38f);
  float lg2 = logits[t + 256] + (1.0f - m2) * (-3.40282347e38f);
  float mx = fmaxf(lg1, lg2);
#pragma unroll
  for (int off = 32; off > 0; off >>= 1) mx = fmaxf(mx, __shfl_xor(mx, off));
  if (l == 0) red[w] = mx;
  __syncthreads();
  float rmax = fmaxf(fmaxf(red[0], red[1]), fmaxf(red[2], red[3]));
  float e1 = __expf(lg1 - rmax);
  float e2 = __expf(lg2 - rmax);
  float s = e1 + e2;
#pragma unroll
  for (int off = 32; off > 0; off >>= 1) s += __shfl_xor(s, off);
  if (l == 0) red[4 + w] = s;
  __syncthreads();
  float inv = 1.0f / (red[4] + red[5] + red[6] + red[7]);
  probs[(size_t)rj * S_ + t]       = (_Float16)(e1 * inv);
  probs[(size_t)rj * S_ + t + 256] = (_Float16)(e2 * inv);
}

// ---------------------------------------------------------------------------
// fp16 MFMA GEMM, in-block split-K/4: 1024 thr = 4 groups x 4 waves.
// Group g covers K-quarter g; private 32KB LDS ring (4 x 8KB), depth-3
// prefetch, counted vmcnt. f32 cross-group reduce via LDS, group 0 epilogue.
// ---------------------------------------------------------------------------
template <bool HASA1, bool RELU, bool FINAL, bool OUTH>
__global__ __launch_bounds__(1024) void mfma_gemm_kernel(
    const _Float16* __restrict__ A0, const _Float16* __restrict__ A1,
    const _Float16* __restrict__ Bt, const float* __restrict__ bias,
    const float* __restrict__ alpha_ptr, void* __restrict__ Cout,
    int M, int N, int K0, int K1,
    long aB0, long aB1, long bB, long cB) {
  __shared__ __attribute__((aligned(16))) char smem[131072];
  const int t = threadIdx.x;
  const int w = t >> 6, l = t & 63;
  const int g = w >> 2, wq = w & 3;
  const int K = K0 + K1;
  const int KQ = K >> 2;
  const int NT = KQ >> 5;
  const int n0 = blockIdx.x * 64, m0 = blockIdx.y * 64;
  const int zb = blockIdx.z;
  const _Float16* A0b = A0 + (size_t)zb * aB0;
  const _Float16* A1b = HASA1 ? (A1 + (size_t)zb * aB1) : nullptr;
  const _Float16* Btb = Bt + (size_t)zb * bB;
  char* gls = smem + (g << 15);

  const int sr = (wq << 4) + (l >> 2);
  const int sk = ((l & 3) ^ ((l >> 3) & 3)) << 3;

  const int mq = wq >> 1, nq = wq & 1;
  int offA[2], offB[2];
#pragma unroll
  for (int i = 0; i < 2; ++i) {
    int ra = mq * 32 + i * 16 + (l & 15);
    offA[i] = ra * 64 + (((l >> 4) ^ ((ra >> 1) & 3)) << 4);
    int rb = nq * 32 + i * 16 + (l & 15);
    offB[i] = 4096 + rb * 64 + (((l >> 4) ^ ((rb >> 1) & 3)) << 4);
  }

  f32x4 acc[2][2] = {};

  auto stage = [&](int tt) {
    char* buf = gls + (tt & 3) * 8192;
    int kg = g * KQ + (tt << 5) + sk;
    const _Float16* ga;
    if (HASA1 && kg >= K0) ga = A1b + (size_t)(m0 + sr) * K1 + (kg - K0);
    else                   ga = A0b + (size_t)(m0 + sr) * K0 + kg;
    __builtin_amdgcn_global_load_lds(
        (const __attribute__((address_space(1))) void*)ga,
        (__attribute__((address_space(3))) void*)(buf + (wq << 10)), 16, 0, 0);
    const _Float16* gb = Btb + (size_t)(n0 + sr) * K + kg;
    __builtin_amdgcn_global_load_lds(
        (const __attribute__((address_space(1))) void*)gb,
        (__attribute__((address_space(3))) void*)(buf + 4096 + (wq << 10)), 16, 0, 0);
  };

  stage(0);
  if (NT > 1) stage(1);
  if (NT > 2) stage(2);

  for (int tt = 0; tt < NT; ++tt) {
    if (tt + 2 < NT)      asm volatile("s_waitcnt vmcnt(4)" ::: "memory");
    else if (tt + 1 < NT) asm volatile("s_waitcnt vmcnt(2)" ::: "memory");
    else                  asm volatile("s_waitcnt vmcnt(0)" ::: "memory");
    __builtin_amdgcn_s_barrier();
    __builtin_amdgcn_sched_barrier(0);
    const char* buf = gls + (tt & 3) * 8192;
    half8 a0 = *(const half8*)(buf + offA[0]);
    half8 a1 = *(const half8*)(buf + offA[1]);
    half8 b0 = *(const half8*)(buf + offB[0]);
    half8 b1v = *(const half8*)(buf + offB[1]);
    __builtin_amdgcn_s_setprio(1);
    acc[0][0] = __builtin_amdgcn_mfma_f32_16x16x32_f16(a0, b0, acc[0][0], 0, 0, 0);
    acc[0][1] = __builtin_amdgcn_mfma_f32_16x16x32_f16(a0, b1v, acc[0][1], 0, 0, 0);
    acc[1][0] = __builtin_amdgcn_mfma_f32_16x16x32_f16(a1, b0, acc[1][0], 0, 0, 0);
    acc[1][1] = __builtin_amdgcn_mfma_f32_16x16x32_f16(a1, b1v, acc[1][1], 0, 0, 0);
    __builtin_amdgcn_s_setprio(0);
    if (tt + 3 < NT) stage(tt + 3);
  }

  // cross-group K reduction through LDS (overlays rings, now dead)
  const int lr = l & 15, lq = l >> 4;
  float* redm = (float*)smem;   // 3 x [64][68]
  __syncthreads();
  if (g > 0) {
    float* rb = redm + (g - 1) * 64 * 68;
#pragma unroll
    for (int mi = 0; mi < 2; ++mi)
#pragma unroll
      for (int ni = 0; ni < 2; ++ni)
#pragma unroll
        for (int rg = 0; rg < 4; ++rg)
          rb[(mq * 32 + mi * 16 + lq * 4 + rg) * 68 + nq * 32 + ni * 16 + lr] =
              acc[mi][ni][rg];
  }
  __syncthreads();
  if (g == 0) {
    const float alpha = FINAL ? *alpha_ptr : 1.0f;
    const size_t cbase = (size_t)zb * cB;
#pragma unroll
    for (int mi = 0; mi < 2; ++mi)
#pragma unroll
      for (int ni = 0; ni < 2; ++ni) {
        int col = n0 + nq * 32 + ni * 16 + lr;
        float bv = bias ? bias[col] : 0.0f;
#pragma unroll
        for (int rg = 0; rg < 4; ++rg) {
          int row = m0 + mq * 32 + mi * 16 + lq * 4 + rg;
          int ri = (mq * 32 + mi * 16 + lq * 4 + rg) * 68 + nq * 32 + ni * 16 + lr;
          float x = acc[mi][ni][rg] + redm[ri] + redm[64 * 68 + ri] +
                    redm[2 * 64 * 68 + ri] + bv;
          if (RELU) x = fmaxf(x, 0.f);
          if (FINAL) x *= alpha;
          if (OUTH)
            ((_Float16*)Cout)[cbase + (size_t)row * N + col] = (_Float16)x;
          else
            ((float*)Cout)[cbase + (size_t)row * N + col] = x;
        }
      }
  }
}

// ---------------------------------------------------------------------------
extern "C" void kernel_launch(void* const* d_in, const int* in_sizes, int n_in,
                              void* d_out, int out_size, void* d_ws, size_t ws_size,
                              hipStream_t stream) {
  const float* Hj   = (const float*)d_in[0];
  const float* Hi   = (const float*)d_in[1];
  const float* mask = (const float*)d_in[2];
  const float* pj   = (const float*)d_in[3];
  const float* pi   = (const float*)d_in[4];
  const float* W1   = (const float*)d_in[5];
  const float* b1   = (const float*)d_in[6];
  const float* W2   = (const float*)d_in[7];
  // d_in[8] = b2: uniform over keys -> softmax invariant, unused
  const float* Wv1  = (const float*)d_in[9];
  const float* bv1  = (const float*)d_in[10];
  const float* Wv2  = (const float*)d_in[11];
  const float* bv2  = (const float*)d_in[12];
  const float* alpha = (const float*)d_in[13];

  char* w = (char*)d_ws;
  float* Zj  = (float*)w;            w += (size_t)ROWS * D_ * 4;
  float* Zi  = (float*)w;            w += (size_t)ROWS * D_ * 4;
  _Float16* Wimg   = (_Float16*)w;   w += (size_t)1024 * 16;
  _Float16* probsH = (_Float16*)w;   w += (size_t)B_ * S_ * S_ * 2;
  _Float16* HjH    = (_Float16*)w;   w += (size_t)ROWS * HDIM * 2;
  _Float16* HiT    = (_Float16*)w;   w += (size_t)B_ * HDIM * S_ * 2;
  _Float16* Wv1T   = (_Float16*)w;   w += (size_t)HDIM * 2 * HDIM * 2;
  _Float16* Wv2T   = (_Float16*)w;   w += (size_t)HDIM * HDIM * 2;
  _Float16* ctxH   = (_Float16*)w;   w += (size_t)ROWS * HDIM * 2;
  _Float16* hidH   = (_Float16*)w;   w += (size_t)ROWS * HDIM * 2;
  float* out = (float*)d_out;

  // all dtype prep + projections in one launch
  prep_kernel<<<3076, 256, 0, stream>>>(Hj, Hi, pj, pi, W1, Wv1, Wv2,
                                        HjH, HiT, Wv1T, Wv2T, Wimg, Zj, Zi);

  pair_fused_kernel<<<ROWS, 256, 0, stream>>>(Zj, Zi, W1, b1, W2, Wimg,
                                              mask, probsH);

  // ctx[b] = probs[b] @ Hi[b]   (M=512, N=1024, K=512) -> fp16
  mfma_gemm_kernel<false, false, false, true><<<dim3(16, 8, 2), 1024, 0, stream>>>(
      probsH, nullptr, HiT, nullptr, nullptr, ctxH,
      S_, HDIM, S_, 0, (long)S_ * S_, 0, (long)HDIM * S_, (long)S_ * HDIM);
  // hidden = relu([ctx | Hj] @ Wv1 + bv1)   (M=1024, N=1024, K=2048) -> fp16
  mfma_gemm_kernel<true, true, false, true><<<dim3(16, 16, 1), 1024, 0, stream>>>(
      ctxH, HjH, Wv1T, bv1, nullptr, hidH,
      ROWS, HDIM, HDIM, HDIM, 0, 0, 0, 0);
  // out = alpha * (hidden @ Wv2 + bv2)      (M=1024, N=1024, K=1024) -> fp32
  mfma_gemm_kernel<false, false, true, false><<<dim3(16, 16, 1), 1024, 0, stream>>>(
      hidH, nullptr, Wv2T, bv2, alpha, out,
      ROWS, HDIM, HDIM, 0, 0, 0, 0, 0);
}

// Round 6
// 81.335 us; speedup vs baseline: 1.0422x; 1.0422x over previous
//
#include <hip/hip_runtime.h>
#include <math.h>

#define B_    2
#define S_    512
#define HDIM  1024
#define D_    24      // proj dim
#define M_    96      // pair-MLP hidden
#define ROWS  (B_*S_) // 1024

typedef _Float16 half8 __attribute__((ext_vector_type(8)));
typedef float    f32x4 __attribute__((ext_vector_type(4)));
typedef unsigned short ushort8 __attribute__((ext_vector_type(8)));

// ---------------------------------------------------------------------------
// 64x64 fp32->fp16 transpose tile through fp16 LDS (stride-72 rows)
// ---------------------------------------------------------------------------
__device__ __forceinline__ void transpose_tile64(
    const float* __restrict__ in, _Float16* __restrict__ out,
    int R, int C, int xt, int yt, _Float16* tileh, int t) {
  int R0 = yt * 64, C0 = xt * 64;
  {
    int r = t >> 4, c4 = (t & 15) * 4;
#pragma unroll
    for (int i = 0; i < 4; ++i) {
      float4 v = *(const float4*)(in + (size_t)(R0 + r + i * 16) * C + C0 + c4);
      _Float16 o[4] = {(_Float16)v.x, (_Float16)v.y, (_Float16)v.z, (_Float16)v.w};
      *(ushort4*)(tileh + (r + i * 16) * 72 + c4) = *(ushort4*)o;
    }
  }
  __syncthreads();
  {
    int r0 = (t & 7) * 8;
#pragma unroll
    for (int p = 0; p < 2; ++p) {
      int c = p * 32 + (t >> 3);
      _Float16 o[8];
#pragma unroll
      for (int e = 0; e < 8; ++e) o[e] = tileh[(r0 + e) * 72 + c];
      *(ushort8*)(out + (size_t)(C0 + c) * R + R0 + r0) = *(ushort8*)o;
    }
  }
}

// ---------------------------------------------------------------------------
// MFMA projection: Z[128 rows][24] = H[128 rows][1024] @ P[1024][24]
// P staged once per block into LDS as wave-linear fragments (zero-pad d>=24):
//  slot s = ((step*2+nt)*64 + hi*16 + lo), 16B each, 4096 slots = 64 KB.
// A-fragments: direct fp32 global loads + cvt. Optionally emits fp16 H image.
// No barriers in K-loop; waves independent. C: col=lane&15, row=(l>>4)*4+rg.
// ---------------------------------------------------------------------------
template <bool EMITH>
__device__ __forceinline__ void proj_mfma(
    const float* __restrict__ H, const float* __restrict__ P,
    float* __restrict__ Z, _Float16* __restrict__ Himg,
    int r0, char* smem, int t) {
  // stage P fragments
  for (int q = 0; q < 16; ++q) {
    int s = t + q * 256;
    int lo = s & 15, hi = (s >> 4) & 3, nt = (s >> 6) & 1, step = s >> 7;
    int d = nt * 16 + lo;
    half8 v = {};
    if (d < D_) {
#pragma unroll
      for (int e = 0; e < 8; ++e)
        v[e] = (_Float16)P[(size_t)(step * 32 + hi * 8 + e) * D_ + d];
    }
    *(half8*)(smem + s * 16) = v;
  }
  __syncthreads();

  const int w = t >> 6, l = t & 63;
  const int lo = l & 15, hi = l >> 4;
  f32x4 acc[2][2] = {};
  for (int step = 0; step < 32; ++step) {
    half8 a8[2];
#pragma unroll
    for (int m2 = 0; m2 < 2; ++m2) {
      int row = r0 + (w * 2 + m2) * 16 + lo;
      const float* src = H + (size_t)row * HDIM + step * 32 + hi * 8;
      float4 v0 = *(const float4*)src;
      float4 v1 = *(const float4*)(src + 4);
      a8[m2][0] = (_Float16)v0.x; a8[m2][1] = (_Float16)v0.y;
      a8[m2][2] = (_Float16)v0.z; a8[m2][3] = (_Float16)v0.w;
      a8[m2][4] = (_Float16)v1.x; a8[m2][5] = (_Float16)v1.y;
      a8[m2][6] = (_Float16)v1.z; a8[m2][7] = (_Float16)v1.w;
      if (EMITH)
        *(half8*)(Himg + (size_t)row * HDIM + step * 32 + hi * 8) = a8[m2];
    }
#pragma unroll
    for (int nt = 0; nt < 2; ++nt) {
      half8 b8 = *(const half8*)(smem + (((step * 2 + nt) * 64) + l) * 16);
#pragma unroll
      for (int m2 = 0; m2 < 2; ++m2)
        acc[m2][nt] = __builtin_amdgcn_mfma_f32_16x16x32_f16(a8[m2], b8, acc[m2][nt], 0, 0, 0);
    }
  }
#pragma unroll
  for (int m2 = 0; m2 < 2; ++m2)
#pragma unroll
    for (int nt = 0; nt < 2; ++nt) {
      int d = nt * 16 + lo;
      if (d < D_) {
#pragma unroll
        for (int rg = 0; rg < 4; ++rg) {
          int row = r0 + (w * 2 + m2) * 16 + hi * 4 + rg;
          Z[(size_t)row * D_ + d] = acc[m2][nt][rg];
        }
      }
    }
}

// ---------------------------------------------------------------------------
// Merged prep kernel: blockIdx ranges
//  [0,4)        : Wimg (fp16 subtiled image of W1 rows 24..95 + zero pad)
//  [4,260)      : HiT 64x64 tiles (128 per batch)
//  [260,772)    : Wv1T tiles
//  [772,1028)   : Wv2T tiles
//  [1028,1036)  : proj Zj (+ HjH emit), 128 rows per block
//  [1036,1044)  : proj Zi, 128 rows per block
// ---------------------------------------------------------------------------
__global__ __launch_bounds__(256) void prep_kernel(
    const float* __restrict__ Hj, const float* __restrict__ Hi,
    const float* __restrict__ pj, const float* __restrict__ pi,
    const float* __restrict__ W1, const float* __restrict__ Wv1,
    const float* __restrict__ Wv2,
    _Float16* __restrict__ HjH, _Float16* __restrict__ HiT,
    _Float16* __restrict__ Wv1T, _Float16* __restrict__ Wv2T,
    _Float16* __restrict__ Wimg, float* __restrict__ Zj,
    float* __restrict__ Zi) {
  __shared__ __attribute__((aligned(16))) char smem[65536];
  const int bid = blockIdx.x;
  const int t = threadIdx.x;

  if (bid < 4) {
    int c = bid * 256 + t;   // 0..1023
    half8 v = {};
    if (c < 864) {
      int kc = c / 96, m = c - kc * 96;
#pragma unroll
      for (int e = 0; e < 8; ++e)
        v[e] = (_Float16)W1[(24 + kc * 8 + e) * M_ + m];
    }
    *(half8*)(Wimg + (size_t)c * 8) = v;
  } else if (bid < 260) {
    int id = bid - 4;
    int z = id >> 7, rem = id & 127;   // 16 x 8 tiles per batch
    transpose_tile64(Hi + (size_t)z * S_ * HDIM, HiT + (size_t)z * HDIM * S_,
                     S_, HDIM, rem & 15, rem >> 4, (_Float16*)smem, t);
  } else if (bid < 772) {
    int id = bid - 260;                // 16 x 32 tiles
    transpose_tile64(Wv1, Wv1T, 2 * HDIM, HDIM, id & 15, id >> 4, (_Float16*)smem, t);
  } else if (bid < 1028) {
    int id = bid - 772;                // 16 x 16 tiles
    transpose_tile64(Wv2, Wv2T, HDIM, HDIM, id & 15, id >> 4, (_Float16*)smem, t);
  } else if (bid < 1036) {
    proj_mfma<true>(Hj, pj, Zj, HjH, (bid - 1028) * 128, smem, t);
  } else {
    proj_mfma<false>(Hi, pi, Zi, nullptr, (bid - 1036) * 128, smem, t);
  }
}

// ---------------------------------------------------------------------------
// Fused pair-MLP + softmax. One block per j-row (1024 blocks, 256 thr).
// C = Wbig(M=96h) x F(N=keys): relu.W2 reduce = 24 in-lane FMAs + 2 shfl.
// ---------------------------------------------------------------------------
#define FOFFB   0                       // 10*256*16 = 40960
#define WOFFB   40960                   // 1024 chunks * 16 = 16384
#define ZOFFB   (WOFFB + 960*16)        // zero chunk
#define LOGOFFB (WOFFB + 16384)         // 512 f32 logits
#define ZJOFFB  (LOGOFFB + 2048)        // 24 f32
#define W2OFFB  (ZJOFFB + 96)           // 96 f32
#define REDOFFB (W2OFFB + 384)          // 8 f32
#define LDSB    (REDOFFB + 32)

__global__ __launch_bounds__(256) void pair_fused_kernel(
    const float* __restrict__ Zj, const float* __restrict__ Zi,
    const float* __restrict__ W1, const float* __restrict__ b1,
    const float* __restrict__ W2, const _Float16* __restrict__ Wimg,
    const float* __restrict__ mask, _Float16* __restrict__ probs) {
  __shared__ __attribute__((aligned(16))) char smem[LDSB];
  const int t = threadIdx.x;
  const int w = t >> 6, l = t & 63;
  const int lo = l & 15, hi = l >> 4;
  const int rj = blockIdx.x;
  const int b = rj >> 9;

  // stage weight image -> LDS (wave-linear dest)
#pragma unroll
  for (int r = 0; r < 4; ++r) {
    const _Float16* src = Wimg + (size_t)(r * 256 + w * 64 + l) * 8;
    __builtin_amdgcn_global_load_lds(
        (const __attribute__((address_space(1))) void*)src,
        (__attribute__((address_space(3))) void*)(smem + WOFFB + (r * 256 + w * 64) * 16),
        16, 0, 0);
  }
  float* zjL    = (float*)(smem + ZJOFFB);
  float* W2s    = (float*)(smem + W2OFFB);
  float* logits = (float*)(smem + LOGOFFB);
  float* red    = (float*)(smem + REDOFFB);
  if (t < D_) zjL[t] = Zj[(size_t)rj * D_ + t];
  if (t < M_) W2s[t] = W2[t];
  float aj = 0.f;
  if (t < M_) {
    aj = b1[t];
#pragma unroll
    for (int d = 0; d < D_; ++d)
      aj = fmaf(Zj[(size_t)rj * D_ + d], W1[d * M_ + t], aj);
  }
  __syncthreads();   // staging + zjL/W2s visible
  if (t < M_) {
    half8 v = {};
    v[0] = (_Float16)aj;
    *(half8*)(smem + WOFFB + (864 + t) * 16) = v;  // Aj row at K=72
  }

  half8 wf[6][3];
  float w2r[6][4];

  for (int p = 0; p < 2; ++p) {
    // ---- feature build: thread owns key i = p*256 + t ----
    {
      int i = p * 256 + t;
      const float* zi = Zi + (size_t)(b * S_ + i) * D_;
      float ziv[D_];
#pragma unroll
      for (int q = 0; q < 6; ++q) {
        float4 v = ((const float4*)zi)[q];
        ziv[q * 4 + 0] = v.x; ziv[q * 4 + 1] = v.y;
        ziv[q * 4 + 2] = v.z; ziv[q * 4 + 3] = v.w;
      }
#pragma unroll
      for (int kc = 0; kc < 3; ++kc) {
        half8 v;
#pragma unroll
        for (int e = 0; e < 8; ++e) v[e] = (_Float16)ziv[kc * 8 + e];
        *(half8*)(smem + FOFFB + (kc * 256 + t) * 16) = v;
      }
#pragma unroll
      for (int kc = 0; kc < 3; ++kc) {
        half8 v;
#pragma unroll
        for (int e = 0; e < 8; ++e) {
          int d = kc * 8 + e;
          v[e] = (_Float16)(zjL[d] * ziv[d]);
        }
        *(half8*)(smem + FOFFB + ((kc + 3) * 256 + t) * 16) = v;
      }
#pragma unroll
      for (int kc = 0; kc < 3; ++kc) {
        half8 v;
#pragma unroll
        for (int e = 0; e < 8; ++e) {
          int d = kc * 8 + e;
          v[e] = (_Float16)fabsf(zjL[d] - ziv[d]);
        }
        *(half8*)(smem + FOFFB + ((kc + 6) * 256 + t) * 16) = v;
      }
      if (p == 0) {
        half8 v = {};
        v[0] = (_Float16)1.0f;
        *(half8*)(smem + FOFFB + (9 * 256 + t) * 16) = v;
      }
    }
    __syncthreads();

    if (p == 0) {   // cache W fragments + W2 slice in regs (const across passes)
#pragma unroll
      for (int mh = 0; mh < 6; ++mh) {
#pragma unroll
        for (int ks = 0; ks < 3; ++ks) {
          int kc = ks * 4 + hi;
          int off = (kc < 10) ? (WOFFB + (kc * 96 + mh * 16 + lo) * 16) : ZOFFB;
          wf[mh][ks] = *(const half8*)(smem + off);
        }
#pragma unroll
        for (int r = 0; r < 4; ++r) w2r[mh][r] = W2s[mh * 16 + hi * 4 + r];
      }
    }

    // ---- MFMA: wave w owns keys w*64 .. w*64+63 (4 N-tiles) ----
#pragma unroll
    for (int nt = 0; nt < 4; ++nt) {
      half8 ff[3];
#pragma unroll
      for (int ks = 0; ks < 3; ++ks) {
        int kc = ks * 4 + hi;
        int off = (kc < 10) ? (FOFFB + (kc * 256 + w * 64 + nt * 16 + lo) * 16) : ZOFFB;
        ff[ks] = *(const half8*)(smem + off);
      }
      f32x4 a6[6] = {};
      __builtin_amdgcn_s_setprio(1);
#pragma unroll
      for (int ks = 0; ks < 3; ++ks)
#pragma unroll
        for (int mh = 0; mh < 6; ++mh)
          a6[mh] = __builtin_amdgcn_mfma_f32_16x16x32_f16(wf[mh][ks], ff[ks], a6[mh], 0, 0, 0);
      __builtin_amdgcn_s_setprio(0);
      float part = 0.f;
#pragma unroll
      for (int mh = 0; mh < 6; ++mh)
#pragma unroll
        for (int r = 0; r < 4; ++r)
          part = fmaf(fmaxf(a6[mh][r], 0.f), w2r[mh][r], part);
      part += __shfl_xor(part, 16);
      part += __shfl_xor(part, 32);
      if (hi == 0) logits[p * 256 + w * 64 + nt * 16 + lo] = part;
    }
    __syncthreads();
  }

  // ---- masked softmax over 512 keys (b2 dropped: shift-invariant) ----
  float m1 = mask[b * S_ + t], m2 = mask[b * S_ + t + 256];
  float lg1 = logits[t]       + (1.0f - m1) * (-3.40282347e38f);
  float lg2 = logits[t + 256] + (1.0f - m2) * (-3.40282347e38f);
  float mx = fmaxf(lg1, lg2);
#pragma unroll
  for (int off = 32; off > 0; off >>= 1) mx = fmaxf(mx, __shfl_xor(mx, off));
  if (l == 0) red[w] = mx;
  __syncthreads();
  float rmax = fmaxf(fmaxf(red[0], red[1]), fmaxf(red[2], red[3]));
  float e1 = __expf(lg1 - rmax);
  float e2 = __expf(lg2 - rmax);
  float s = e1 + e2;
#pragma unroll
  for (int off = 32; off > 0; off >>= 1) s += __shfl_xor(s, off);
  if (l == 0) red[4 + w] = s;
  __syncthreads();
  float inv = 1.0f / (red[4] + red[5] + red[6] + red[7]);
  probs[(size_t)rj * S_ + t]       = (_Float16)(e1 * inv);
  probs[(size_t)rj * S_ + t + 256] = (_Float16)(e2 * inv);
}

// ---------------------------------------------------------------------------
// fp16 MFMA GEMM, in-block split-K/2: 512 thr = 2 groups x 4 waves.
// Group g covers K-half g; private 32KB LDS ring (4 x 8KB), depth-3 prefetch,
// counted vmcnt. f32 cross-group reduce via LDS, epilogue by group 0.
// (proven round-4 configuration)
// ---------------------------------------------------------------------------
template <bool HASA1, bool RELU, bool FINAL, bool OUTH>
__global__ __launch_bounds__(512) void mfma_gemm_kernel(
    const _Float16* __restrict__ A0, const _Float16* __restrict__ A1,
    const _Float16* __restrict__ Bt, const float* __restrict__ bias,
    const float* __restrict__ alpha_ptr, void* __restrict__ Cout,
    int M, int N, int K0, int K1,
    long aB0, long aB1, long bB, long cB) {
  __shared__ __attribute__((aligned(16))) char smem[65536];
  const int t = threadIdx.x;
  const int w = t >> 6, l = t & 63;
  const int g = w >> 2, wq = w & 3;
  const int K = K0 + K1;
  const int KH = K >> 1;
  const int NT = KH >> 5;
  const int n0 = blockIdx.x * 64, m0 = blockIdx.y * 64;
  const int zb = blockIdx.z;
  const _Float16* A0b = A0 + (size_t)zb * aB0;
  const _Float16* A1b = HASA1 ? (A1 + (size_t)zb * aB1) : nullptr;
  const _Float16* Btb = Bt + (size_t)zb * bB;
  char* gls = smem + (g << 15);

  const int sr = (wq << 4) + (l >> 2);
  const int sk = ((l & 3) ^ ((l >> 3) & 3)) << 3;

  const int mq = wq >> 1, nq = wq & 1;
  int offA[2], offB[2];
#pragma unroll
  for (int i = 0; i < 2; ++i) {
    int ra = mq * 32 + i * 16 + (l & 15);
    offA[i] = ra * 64 + (((l >> 4) ^ ((ra >> 1) & 3)) << 4);
    int rb = nq * 32 + i * 16 + (l & 15);
    offB[i] = 4096 + rb * 64 + (((l >> 4) ^ ((rb >> 1) & 3)) << 4);
  }

  f32x4 acc[2][2] = {};

  auto stage = [&](int tt) {
    char* buf = gls + (tt & 3) * 8192;
    int kg = g * KH + (tt << 5) + sk;
    const _Float16* ga;
    if (HASA1 && kg >= K0) ga = A1b + (size_t)(m0 + sr) * K1 + (kg - K0);
    else                   ga = A0b + (size_t)(m0 + sr) * K0 + kg;
    __builtin_amdgcn_global_load_lds(
        (const __attribute__((address_space(1))) void*)ga,
        (__attribute__((address_space(3))) void*)(buf + (wq << 10)), 16, 0, 0);
    const _Float16* gb = Btb + (size_t)(n0 + sr) * K + kg;
    __builtin_amdgcn_global_load_lds(
        (const __attribute__((address_space(1))) void*)gb,
        (__attribute__((address_space(3))) void*)(buf + 4096 + (wq << 10)), 16, 0, 0);
  };

  stage(0);
  stage(1);
  stage(2);

  for (int tt = 0; tt < NT; ++tt) {
    if (tt + 2 < NT)      asm volatile("s_waitcnt vmcnt(4)" ::: "memory");
    else if (tt + 1 < NT) asm volatile("s_waitcnt vmcnt(2)" ::: "memory");
    else                  asm volatile("s_waitcnt vmcnt(0)" ::: "memory");
    __builtin_amdgcn_s_barrier();
    __builtin_amdgcn_sched_barrier(0);
    const char* buf = gls + (tt & 3) * 8192;
    half8 a0 = *(const half8*)(buf + offA[0]);
    half8 a1 = *(const half8*)(buf + offA[1]);
    half8 b0 = *(const half8*)(buf + offB[0]);
    half8 b1v = *(const half8*)(buf + offB[1]);
    acc[0][0] = __builtin_amdgcn_mfma_f32_16x16x32_f16(a0, b0, acc[0][0], 0, 0, 0);
    acc[0][1] = __builtin_amdgcn_mfma_f32_16x16x32_f16(a0, b1v, acc[0][1], 0, 0, 0);
    acc[1][0] = __builtin_amdgcn_mfma_f32_16x16x32_f16(a1, b0, acc[1][0], 0, 0, 0);
    acc[1][1] = __builtin_amdgcn_mfma_f32_16x16x32_f16(a1, b1v, acc[1][1], 0, 0, 0);
    if (tt + 3 < NT) stage(tt + 3);
  }

  // cross-group K reduction through LDS (overlays group-0 ring, now dead)
  const int lr = l & 15, lq = l >> 4;
  float* redm = (float*)smem;   // [64][68]
  __syncthreads();
  if (g == 1) {
#pragma unroll
    for (int mi = 0; mi < 2; ++mi)
#pragma unroll
      for (int ni = 0; ni < 2; ++ni)
#pragma unroll
        for (int rg = 0; rg < 4; ++rg)
          redm[(mq * 32 + mi * 16 + lq * 4 + rg) * 68 + nq * 32 + ni * 16 + lr] =
              acc[mi][ni][rg];
  }
  __syncthreads();
  if (g == 0) {
    const float alpha = FINAL ? *alpha_ptr : 1.0f;
    const size_t cbase = (size_t)zb * cB;
#pragma unroll
    for (int mi = 0; mi < 2; ++mi)
#pragma unroll
      for (int ni = 0; ni < 2; ++ni) {
        int col = n0 + nq * 32 + ni * 16 + lr;
        float bv = bias ? bias[col] : 0.0f;
#pragma unroll
        for (int rg = 0; rg < 4; ++rg) {
          int row = m0 + mq * 32 + mi * 16 + lq * 4 + rg;
          float x = acc[mi][ni][rg] +
                    redm[(mq * 32 + mi * 16 + lq * 4 + rg) * 68 + nq * 32 + ni * 16 + lr] +
                    bv;
          if (RELU) x = fmaxf(x, 0.f);
          if (FINAL) x *= alpha;
          if (OUTH)
            ((_Float16*)Cout)[cbase + (size_t)row * N + col] = (_Float16)x;
          else
            ((float*)Cout)[cbase + (size_t)row * N + col] = x;
        }
      }
  }
}

// ---------------------------------------------------------------------------
extern "C" void kernel_launch(void* const* d_in, const int* in_sizes, int n_in,
                              void* d_out, int out_size, void* d_ws, size_t ws_size,
                              hipStream_t stream) {
  const float* Hj   = (const float*)d_in[0];
  const float* Hi   = (const float*)d_in[1];
  const float* mask = (const float*)d_in[2];
  const float* pj   = (const float*)d_in[3];
  const float* pi   = (const float*)d_in[4];
  const float* W1   = (const float*)d_in[5];
  const float* b1   = (const float*)d_in[6];
  const float* W2   = (const float*)d_in[7];
  // d_in[8] = b2: uniform over keys -> softmax invariant, unused
  const float* Wv1  = (const float*)d_in[9];
  const float* bv1  = (const float*)d_in[10];
  const float* Wv2  = (const float*)d_in[11];
  const float* bv2  = (const float*)d_in[12];
  const float* alpha = (const float*)d_in[13];

  char* w = (char*)d_ws;
  float* Zj  = (float*)w;            w += (size_t)ROWS * D_ * 4;
  float* Zi  = (float*)w;            w += (size_t)ROWS * D_ * 4;
  _Float16* Wimg   = (_Float16*)w;   w += (size_t)1024 * 16;
  _Float16* probsH = (_Float16*)w;   w += (size_t)B_ * S_ * S_ * 2;
  _Float16* HjH    = (_Float16*)w;   w += (size_t)ROWS * HDIM * 2;
  _Float16* HiT    = (_Float16*)w;   w += (size_t)B_ * HDIM * S_ * 2;
  _Float16* Wv1T   = (_Float16*)w;   w += (size_t)HDIM * 2 * HDIM * 2;
  _Float16* Wv2T   = (_Float16*)w;   w += (size_t)HDIM * HDIM * 2;
  _Float16* ctxH   = (_Float16*)w;   w += (size_t)ROWS * HDIM * 2;
  _Float16* hidH   = (_Float16*)w;   w += (size_t)ROWS * HDIM * 2;
  float* out = (float*)d_out;

  // all dtype prep + projections in one launch
  prep_kernel<<<1044, 256, 0, stream>>>(Hj, Hi, pj, pi, W1, Wv1, Wv2,
                                        HjH, HiT, Wv1T, Wv2T, Wimg, Zj, Zi);

  pair_fused_kernel<<<ROWS, 256, 0, stream>>>(Zj, Zi, W1, b1, W2, Wimg,
                                              mask, probsH);

  // ctx[b] = probs[b] @ Hi[b]   (M=512, N=1024, K=512) -> fp16
  mfma_gemm_kernel<false, false, false, true><<<dim3(16, 8, 2), 512, 0, stream>>>(
      probsH, nullptr, HiT, nullptr, nullptr, ctxH,
      S_, HDIM, S_, 0, (long)S_ * S_, 0, (long)HDIM * S_, (long)S_ * HDIM);
  // hidden = relu([ctx | Hj] @ Wv1 + bv1)   (M=1024, N=1024, K=2048) -> fp16
  mfma_gemm_kernel<true, true, false, true><<<dim3(16, 16, 1), 512, 0, stream>>>(
      ctxH, HjH, Wv1T, bv1, nullptr, hidH,
      ROWS, HDIM, HDIM, HDIM, 0, 0, 0, 0);
  // out = alpha * (hidden @ Wv2 + bv2)      (M=1024, N=1024, K=1024) -> fp32
  mfma_gemm_kernel<false, false, true, false><<<dim3(16, 16, 1), 512, 0, stream>>>(
      hidH, nullptr, Wv2T, bv2, alpha, out,
      ROWS, HDIM, HDIM, 0, 0, 0, 0, 0);
}

// Round 7
// 76.067 us; speedup vs baseline: 1.1144x; 1.0692x over previous
//
#include <hip/hip_runtime.h>
#include <math.h>

#define B_    2
#define S_    512
#define HDIM  1024
#define D_    24      // proj dim
#define M_    96      // pair-MLP hidden
#define ROWS  (B_*S_) // 1024

typedef _Float16 half8 __attribute__((ext_vector_type(8)));
typedef float    f32x4 __attribute__((ext_vector_type(4)));
typedef unsigned short ushort8 __attribute__((ext_vector_type(8)));

// ---------------------------------------------------------------------------
// cache-based 64x64 fp32->fp16 transpose (no LDS): lane reads 16 strided
// fp32 (cachelines fully consumed by neighbor lanes; 16KB tile fits L1),
// writes two contiguous ushort8.
// ---------------------------------------------------------------------------
__device__ __forceinline__ void transpose_tile64_cache(
    const float* __restrict__ in, _Float16* __restrict__ out,
    int R, int C, int xt, int yt, int t) {
  int R0 = yt * 64, C0 = xt * 64;
  int c = t >> 2, rq = (t & 3) * 16;
  _Float16 o[16];
  const float* src = in + (size_t)(R0 + rq) * C + C0 + c;
#pragma unroll
  for (int e = 0; e < 16; ++e) o[e] = (_Float16)src[(size_t)e * C];
  _Float16* dst = out + (size_t)(C0 + c) * R + R0 + rq;
  *(ushort8*)dst = *(ushort8*)o;
  *(ushort8*)(dst + 8) = *(ushort8*)&o[8];
}

// ---------------------------------------------------------------------------
// prep kernel (no LDS anywhere): blockIdx ranges
//  [0,4)       : Wimg (fp16 subtiled image of W1 rows 24..95 + zero pad)
//  [4,12)      : PjT/PiT  [32][1024] fp16 (d-major; rows 24..31 zero)
//  [12,268)    : HiT 64x64 tiles (128 per batch)
//  [268,780)   : Wv1T tiles
//  [780,1036)  : Wv2T tiles
// ---------------------------------------------------------------------------
__global__ __launch_bounds__(256) void prep_kernel(
    const float* __restrict__ Hi, const float* __restrict__ pj,
    const float* __restrict__ pi, const float* __restrict__ W1,
    const float* __restrict__ Wv1, const float* __restrict__ Wv2,
    _Float16* __restrict__ HiT, _Float16* __restrict__ Wv1T,
    _Float16* __restrict__ Wv2T, _Float16* __restrict__ Wimg,
    _Float16* __restrict__ PjT, _Float16* __restrict__ PiT) {
  const int bid = blockIdx.x;
  const int t = threadIdx.x;

  if (bid < 4) {
    int c = bid * 256 + t;   // 0..1023
    half8 v = {};
    if (c < 864) {
      int kc = c / 96, m = c - kc * 96;
#pragma unroll
      for (int e = 0; e < 8; ++e)
        v[e] = (_Float16)W1[(24 + kc * 8 + e) * M_ + m];
    }
    *(half8*)(Wimg + (size_t)c * 8) = v;
  } else if (bid < 12) {
    int id = bid - 4;
    const float* P = (id < 4) ? pj : pi;
    _Float16* PT = (id < 4) ? PjT : PiT;
    int k = (id & 3) * 256 + t;
#pragma unroll
    for (int d = 0; d < 32; ++d) {
      float v = (d < D_) ? P[(size_t)k * D_ + d] : 0.0f;
      PT[(size_t)d * 1024 + k] = (_Float16)v;
    }
  } else if (bid < 268) {
    int id = bid - 12;
    int z = id >> 7, rem = id & 127;   // 16 x 8 tiles per batch
    transpose_tile64_cache(Hi + (size_t)z * S_ * HDIM,
                           HiT + (size_t)z * HDIM * S_,
                           S_, HDIM, rem & 15, rem >> 4, t);
  } else if (bid < 780) {
    int id = bid - 268;                // 16 x 32 tiles
    transpose_tile64_cache(Wv1, Wv1T, 2 * HDIM, HDIM, id & 15, id >> 4, t);
  } else {
    int id = bid - 780;                // 16 x 16 tiles
    transpose_tile64_cache(Wv2, Wv2T, HDIM, HDIM, id & 15, id >> 4, t);
  }
}

// ---------------------------------------------------------------------------
// proj kernel: Z[16 rows][24] = H[16 rows][1024] @ P[1024][24] per one-wave
// block. B-fragments are contiguous 16B global loads from PT (L2-resident).
// Hj-blocks also emit the fp16 image of Hj. No LDS, no barriers.
// grid 128 x 64 threads: bid<64 -> Hj/Zj, else Hi/Zi.
// ---------------------------------------------------------------------------
__global__ __launch_bounds__(64) void proj_kernel(
    const float* __restrict__ Hj, const float* __restrict__ Hi,
    const _Float16* __restrict__ PjT, const _Float16* __restrict__ PiT,
    _Float16* __restrict__ HjH, float* __restrict__ Zj,
    float* __restrict__ Zi) {
  const int bid = blockIdx.x;
  const int l = threadIdx.x;
  const int lo = l & 15, hi = l >> 4;
  const bool isj = bid < 64;
  const int r0 = (bid & 63) * 16;
  const float* H = isj ? Hj : Hi;
  const _Float16* PT = isj ? PjT : PiT;
  float* Z = isj ? Zj : Zi;
  const float* hrow = H + (size_t)(r0 + lo) * HDIM;

  f32x4 acc0 = {}, acc1 = {};
  for (int step = 0; step < 32; ++step) {
    const float* src = hrow + step * 32 + hi * 8;
    float4 v0 = *(const float4*)src;
    float4 v1 = *(const float4*)(src + 4);
    half8 a8;
    a8[0] = (_Float16)v0.x; a8[1] = (_Float16)v0.y;
    a8[2] = (_Float16)v0.z; a8[3] = (_Float16)v0.w;
    a8[4] = (_Float16)v1.x; a8[5] = (_Float16)v1.y;
    a8[6] = (_Float16)v1.z; a8[7] = (_Float16)v1.w;
    if (isj)
      *(half8*)(HjH + (size_t)(r0 + lo) * HDIM + step * 32 + hi * 8) = a8;
    half8 b0 = *(const half8*)(PT + (size_t)lo * 1024 + step * 32 + hi * 8);
    half8 b1 = *(const half8*)(PT + (size_t)(16 + lo) * 1024 + step * 32 + hi * 8);
    acc0 = __builtin_amdgcn_mfma_f32_16x16x32_f16(a8, b0, acc0, 0, 0, 0);
    acc1 = __builtin_amdgcn_mfma_f32_16x16x32_f16(a8, b1, acc1, 0, 0, 0);
  }
  // C layout: col = lane&15 (=d), row = (lane>>4)*4 + rg
#pragma unroll
  for (int rg = 0; rg < 4; ++rg) {
    int row = r0 + hi * 4 + rg;
    Z[(size_t)row * D_ + lo] = acc0[rg];
    if (lo < 8) Z[(size_t)row * D_ + 16 + lo] = acc1[rg];
  }
}

// ---------------------------------------------------------------------------
// Fused pair-MLP + softmax. One block per j-row (1024 blocks, 256 thr).
// C = Wbig(M=96h) x F(N=keys): relu.W2 reduce = 24 in-lane FMAs + 2 shfl.
// ---------------------------------------------------------------------------
#define FOFFB   0                       // 10*256*16 = 40960
#define WOFFB   40960                   // 1024 chunks * 16 = 16384
#define ZOFFB   (WOFFB + 960*16)        // zero chunk
#define LOGOFFB (WOFFB + 16384)         // 512 f32 logits
#define ZJOFFB  (LOGOFFB + 2048)        // 24 f32
#define W2OFFB  (ZJOFFB + 96)           // 96 f32
#define REDOFFB (W2OFFB + 384)          // 8 f32
#define LDSB    (REDOFFB + 32)

__global__ __launch_bounds__(256) void pair_fused_kernel(
    const float* __restrict__ Zj, const float* __restrict__ Zi,
    const float* __restrict__ W1, const float* __restrict__ b1,
    const float* __restrict__ W2, const _Float16* __restrict__ Wimg,
    const float* __restrict__ mask, _Float16* __restrict__ probs) {
  __shared__ __attribute__((aligned(16))) char smem[LDSB];
  const int t = threadIdx.x;
  const int w = t >> 6, l = t & 63;
  const int lo = l & 15, hi = l >> 4;
  const int rj = blockIdx.x;
  const int b = rj >> 9;

  // stage weight image -> LDS (wave-linear dest)
#pragma unroll
  for (int r = 0; r < 4; ++r) {
    const _Float16* src = Wimg + (size_t)(r * 256 + w * 64 + l) * 8;
    __builtin_amdgcn_global_load_lds(
        (const __attribute__((address_space(1))) void*)src,
        (__attribute__((address_space(3))) void*)(smem + WOFFB + (r * 256 + w * 64) * 16),
        16, 0, 0);
  }
  float* zjL    = (float*)(smem + ZJOFFB);
  float* W2s    = (float*)(smem + W2OFFB);
  float* logits = (float*)(smem + LOGOFFB);
  float* red    = (float*)(smem + REDOFFB);
  if (t < D_) zjL[t] = Zj[(size_t)rj * D_ + t];
  if (t < M_) W2s[t] = W2[t];
  float aj = 0.f;
  if (t < M_) {
    aj = b1[t];
#pragma unroll
    for (int d = 0; d < D_; ++d)
      aj = fmaf(Zj[(size_t)rj * D_ + d], W1[d * M_ + t], aj);
  }
  __syncthreads();   // staging + zjL/W2s visible
  if (t < M_) {
    half8 v = {};
    v[0] = (_Float16)aj;
    *(half8*)(smem + WOFFB + (864 + t) * 16) = v;  // Aj row at K=72
  }

  half8 wf[6][3];
  float w2r[6][4];

  for (int p = 0; p < 2; ++p) {
    // ---- feature build: thread owns key i = p*256 + t ----
    {
      int i = p * 256 + t;
      const float* zi = Zi + (size_t)(b * S_ + i) * D_;
      float ziv[D_];
#pragma unroll
      for (int q = 0; q < 6; ++q) {
        float4 v = ((const float4*)zi)[q];
        ziv[q * 4 + 0] = v.x; ziv[q * 4 + 1] = v.y;
        ziv[q * 4 + 2] = v.z; ziv[q * 4 + 3] = v.w;
      }
#pragma unroll
      for (int kc = 0; kc < 3; ++kc) {
        half8 v;
#pragma unroll
        for (int e = 0; e < 8; ++e) v[e] = (_Float16)ziv[kc * 8 + e];
        *(half8*)(smem + FOFFB + (kc * 256 + t) * 16) = v;
      }
#pragma unroll
      for (int kc = 0; kc < 3; ++kc) {
        half8 v;
#pragma unroll
        for (int e = 0; e < 8; ++e) {
          int d = kc * 8 + e;
          v[e] = (_Float16)(zjL[d] * ziv[d]);
        }
        *(half8*)(smem + FOFFB + ((kc + 3) * 256 + t) * 16) = v;
      }
#pragma unroll
      for (int kc = 0; kc < 3; ++kc) {
        half8 v;
#pragma unroll
        for (int e = 0; e < 8; ++e) {
          int d = kc * 8 + e;
          v[e] = (_Float16)fabsf(zjL[d] - ziv[d]);
        }
        *(half8*)(smem + FOFFB + ((kc + 6) * 256 + t) * 16) = v;
      }
      if (p == 0) {
        half8 v = {};
        v[0] = (_Float16)1.0f;
        *(half8*)(smem + FOFFB + (9 * 256 + t) * 16) = v;
      }
    }
    __syncthreads();

    if (p == 0) {   // cache W fragments + W2 slice in regs (const across passes)
#pragma unroll
      for (int mh = 0; mh < 6; ++mh) {
#pragma unroll
        for (int ks = 0; ks < 3; ++ks) {
          int kc = ks * 4 + hi;
          int off = (kc < 10) ? (WOFFB + (kc * 96 + mh * 16 + lo) * 16) : ZOFFB;
          wf[mh][ks] = *(const half8*)(smem + off);
        }
#pragma unroll
        for (int r = 0; r < 4; ++r) w2r[mh][r] = W2s[mh * 16 + hi * 4 + r];
      }
    }

    // ---- MFMA: wave w owns keys w*64 .. w*64+63 (4 N-tiles) ----
#pragma unroll
    for (int nt = 0; nt < 4; ++nt) {
      half8 ff[3];
#pragma unroll
      for (int ks = 0; ks < 3; ++ks) {
        int kc = ks * 4 + hi;
        int off = (kc < 10) ? (FOFFB + (kc * 256 + w * 64 + nt * 16 + lo) * 16) : ZOFFB;
        ff[ks] = *(const half8*)(smem + off);
      }
      f32x4 a6[6] = {};
      __builtin_amdgcn_s_setprio(1);
#pragma unroll
      for (int ks = 0; ks < 3; ++ks)
#pragma unroll
        for (int mh = 0; mh < 6; ++mh)
          a6[mh] = __builtin_amdgcn_mfma_f32_16x16x32_f16(wf[mh][ks], ff[ks], a6[mh], 0, 0, 0);
      __builtin_amdgcn_s_setprio(0);
      float part = 0.f;
#pragma unroll
      for (int mh = 0; mh < 6; ++mh)
#pragma unroll
        for (int r = 0; r < 4; ++r)
          part = fmaf(fmaxf(a6[mh][r], 0.f), w2r[mh][r], part);
      part += __shfl_xor(part, 16);
      part += __shfl_xor(part, 32);
      if (hi == 0) logits[p * 256 + w * 64 + nt * 16 + lo] = part;
    }
    __syncthreads();
  }

  // ---- masked softmax over 512 keys (b2 dropped: shift-invariant) ----
  float m1 = mask[b * S_ + t], m2 = mask[b * S_ + t + 256];
  float lg1 = logits[t]       + (1.0f - m1) * (-3.40282347e38f);
  float lg2 = logits[t + 256] + (1.0f - m2) * (-3.40282347e38f);
  float mx = fmaxf(lg1, lg2);
#pragma unroll
  for (int off = 32; off > 0; off >>= 1) mx = fmaxf(mx, __shfl_xor(mx, off));
  if (l == 0) red[w] = mx;
  __syncthreads();
  float rmax = fmaxf(fmaxf(red[0], red[1]), fmaxf(red[2], red[3]));
  float e1 = __expf(lg1 - rmax);
  float e2 = __expf(lg2 - rmax);
  float s = e1 + e2;
#pragma unroll
  for (int off = 32; off > 0; off >>= 1) s += __shfl_xor(s, off);
  if (l == 0) red[4 + w] = s;
  __syncthreads();
  float inv = 1.0f / (red[4] + red[5] + red[6] + red[7]);
  probs[(size_t)rj * S_ + t]       = (_Float16)(e1 * inv);
  probs[(size_t)rj * S_ + t + 256] = (_Float16)(e2 * inv);
}

// ---------------------------------------------------------------------------
// fp16 MFMA GEMM, in-block split-K/2: 512 thr = 2 groups x 4 waves.
// (proven round-4 configuration)
// ---------------------------------------------------------------------------
template <bool HASA1, bool RELU, bool FINAL, bool OUTH>
__global__ __launch_bounds__(512) void mfma_gemm_kernel(
    const _Float16* __restrict__ A0, const _Float16* __restrict__ A1,
    const _Float16* __restrict__ Bt, const float* __restrict__ bias,
    const float* __restrict__ alpha_ptr, void* __restrict__ Cout,
    int M, int N, int K0, int K1,
    long aB0, long aB1, long bB, long cB) {
  __shared__ __attribute__((aligned(16))) char smem[65536];
  const int t = threadIdx.x;
  const int w = t >> 6, l = t & 63;
  const int g = w >> 2, wq = w & 3;
  const int K = K0 + K1;
  const int KH = K >> 1;
  const int NT = KH >> 5;
  const int n0 = blockIdx.x * 64, m0 = blockIdx.y * 64;
  const int zb = blockIdx.z;
  const _Float16* A0b = A0 + (size_t)zb * aB0;
  const _Float16* A1b = HASA1 ? (A1 + (size_t)zb * aB1) : nullptr;
  const _Float16* Btb = Bt + (size_t)zb * bB;
  char* gls = smem + (g << 15);

  const int sr = (wq << 4) + (l >> 2);
  const int sk = ((l & 3) ^ ((l >> 3) & 3)) << 3;

  const int mq = wq >> 1, nq = wq & 1;
  int offA[2], offB[2];
#pragma unroll
  for (int i = 0; i < 2; ++i) {
    int ra = mq * 32 + i * 16 + (l & 15);
    offA[i] = ra * 64 + (((l >> 4) ^ ((ra >> 1) & 3)) << 4);
    int rb = nq * 32 + i * 16 + (l & 15);
    offB[i] = 4096 + rb * 64 + (((l >> 4) ^ ((rb >> 1) & 3)) << 4);
  }

  f32x4 acc[2][2] = {};

  auto stage = [&](int tt) {
    char* buf = gls + (tt & 3) * 8192;
    int kg = g * KH + (tt << 5) + sk;
    const _Float16* ga;
    if (HASA1 && kg >= K0) ga = A1b + (size_t)(m0 + sr) * K1 + (kg - K0);
    else                   ga = A0b + (size_t)(m0 + sr) * K0 + kg;
    __builtin_amdgcn_global_load_lds(
        (const __attribute__((address_space(1))) void*)ga,
        (__attribute__((address_space(3))) void*)(buf + (wq << 10)), 16, 0, 0);
    const _Float16* gb = Btb + (size_t)(n0 + sr) * K + kg;
    __builtin_amdgcn_global_load_lds(
        (const __attribute__((address_space(1))) void*)gb,
        (__attribute__((address_space(3))) void*)(buf + 4096 + (wq << 10)), 16, 0, 0);
  };

  stage(0);
  stage(1);
  stage(2);

  for (int tt = 0; tt < NT; ++tt) {
    if (tt + 2 < NT)      asm volatile("s_waitcnt vmcnt(4)" ::: "memory");
    else if (tt + 1 < NT) asm volatile("s_waitcnt vmcnt(2)" ::: "memory");
    else                  asm volatile("s_waitcnt vmcnt(0)" ::: "memory");
    __builtin_amdgcn_s_barrier();
    __builtin_amdgcn_sched_barrier(0);
    const char* buf = gls + (tt & 3) * 8192;
    half8 a0 = *(const half8*)(buf + offA[0]);
    half8 a1 = *(const half8*)(buf + offA[1]);
    half8 b0 = *(const half8*)(buf + offB[0]);
    half8 b1v = *(const half8*)(buf + offB[1]);
    acc[0][0] = __builtin_amdgcn_mfma_f32_16x16x32_f16(a0, b0, acc[0][0], 0, 0, 0);
    acc[0][1] = __builtin_amdgcn_mfma_f32_16x16x32_f16(a0, b1v, acc[0][1], 0, 0, 0);
    acc[1][0] = __builtin_amdgcn_mfma_f32_16x16x32_f16(a1, b0, acc[1][0], 0, 0, 0);
    acc[1][1] = __builtin_amdgcn_mfma_f32_16x16x32_f16(a1, b1v, acc[1][1], 0, 0, 0);
    if (tt + 3 < NT) stage(tt + 3);
  }

  // cross-group K reduction through LDS (overlays group-0 ring, now dead)
  const int lr = l & 15, lq = l >> 4;
  float* redm = (float*)smem;   // [64][68]
  __syncthreads();
  if (g == 1) {
#pragma unroll
    for (int mi = 0; mi < 2; ++mi)
#pragma unroll
      for (int ni = 0; ni < 2; ++ni)
#pragma unroll
        for (int rg = 0; rg < 4; ++rg)
          redm[(mq * 32 + mi * 16 + lq * 4 + rg) * 68 + nq * 32 + ni * 16 + lr] =
              acc[mi][ni][rg];
  }
  __syncthreads();
  if (g == 0) {
    const float alpha = FINAL ? *alpha_ptr : 1.0f;
    const size_t cbase = (size_t)zb * cB;
#pragma unroll
    for (int mi = 0; mi < 2; ++mi)
#pragma unroll
      for (int ni = 0; ni < 2; ++ni) {
        int col = n0 + nq * 32 + ni * 16 + lr;
        float bv = bias ? bias[col] : 0.0f;
#pragma unroll
        for (int rg = 0; rg < 4; ++rg) {
          int row = m0 + mq * 32 + mi * 16 + lq * 4 + rg;
          float x = acc[mi][ni][rg] +
                    redm[(mq * 32 + mi * 16 + lq * 4 + rg) * 68 + nq * 32 + ni * 16 + lr] +
                    bv;
          if (RELU) x = fmaxf(x, 0.f);
          if (FINAL) x *= alpha;
          if (OUTH)
            ((_Float16*)Cout)[cbase + (size_t)row * N + col] = (_Float16)x;
          else
            ((float*)Cout)[cbase + (size_t)row * N + col] = x;
        }
      }
  }
}

// ---------------------------------------------------------------------------
extern "C" void kernel_launch(void* const* d_in, const int* in_sizes, int n_in,
                              void* d_out, int out_size, void* d_ws, size_t ws_size,
                              hipStream_t stream) {
  const float* Hj   = (const float*)d_in[0];
  const float* Hi   = (const float*)d_in[1];
  const float* mask = (const float*)d_in[2];
  const float* pj   = (const float*)d_in[3];
  const float* pi   = (const float*)d_in[4];
  const float* W1   = (const float*)d_in[5];
  const float* b1   = (const float*)d_in[6];
  const float* W2   = (const float*)d_in[7];
  // d_in[8] = b2: uniform over keys -> softmax invariant, unused
  const float* Wv1  = (const float*)d_in[9];
  const float* bv1  = (const float*)d_in[10];
  const float* Wv2  = (const float*)d_in[11];
  const float* bv2  = (const float*)d_in[12];
  const float* alpha = (const float*)d_in[13];

  char* w = (char*)d_ws;
  float* Zj  = (float*)w;            w += (size_t)ROWS * D_ * 4;
  float* Zi  = (float*)w;            w += (size_t)ROWS * D_ * 4;
  _Float16* Wimg   = (_Float16*)w;   w += (size_t)1024 * 16;
  _Float16* PjT    = (_Float16*)w;   w += (size_t)32 * 1024 * 2;
  _Float16* PiT    = (_Float16*)w;   w += (size_t)32 * 1024 * 2;
  _Float16* probsH = (_Float16*)w;   w += (size_t)B_ * S_ * S_ * 2;
  _Float16* HjH    = (_Float16*)w;   w += (size_t)ROWS * HDIM * 2;
  _Float16* HiT    = (_Float16*)w;   w += (size_t)B_ * HDIM * S_ * 2;
  _Float16* Wv1T   = (_Float16*)w;   w += (size_t)HDIM * 2 * HDIM * 2;
  _Float16* Wv2T   = (_Float16*)w;   w += (size_t)HDIM * HDIM * 2;
  _Float16* ctxH   = (_Float16*)w;   w += (size_t)ROWS * HDIM * 2;
  _Float16* hidH   = (_Float16*)w;   w += (size_t)ROWS * HDIM * 2;
  float* out = (float*)d_out;

  // dtype prep (transposes, weight images) — no LDS, cache-based
  prep_kernel<<<1036, 256, 0, stream>>>(Hi, pj, pi, W1, Wv1, Wv2,
                                        HiT, Wv1T, Wv2T, Wimg, PjT, PiT);
  // projections (consumes PjT/PiT -> separate launch for ordering)
  proj_kernel<<<128, 64, 0, stream>>>(Hj, Hi, PjT, PiT, HjH, Zj, Zi);

  pair_fused_kernel<<<ROWS, 256, 0, stream>>>(Zj, Zi, W1, b1, W2, Wimg,
                                              mask, probsH);

  // ctx[b] = probs[b] @ Hi[b]   (M=512, N=1024, K=512) -> fp16
  mfma_gemm_kernel<false, false, false, true><<<dim3(16, 8, 2), 512, 0, stream>>>(
      probsH, nullptr, HiT, nullptr, nullptr, ctxH,
      S_, HDIM, S_, 0, (long)S_ * S_, 0, (long)HDIM * S_, (long)S_ * HDIM);
  // hidden = relu([ctx | Hj] @ Wv1 + bv1)   (M=1024, N=1024, K=2048) -> fp16
  mfma_gemm_kernel<true, true, false, true><<<dim3(16, 16, 1), 512, 0, stream>>>(
      ctxH, HjH, Wv1T, bv1, nullptr, hidH,
      ROWS, HDIM, HDIM, HDIM, 0, 0, 0, 0);
  // out = alpha * (hidden @ Wv2 + bv2)      (M=1024, N=1024, K=1024) -> fp32
  mfma_gemm_kernel<false, false, true, false><<<dim3(16, 16, 1), 512, 0, stream>>>(
      hidH, nullptr, Wv2T, bv2, alpha, out,
      ROWS, HDIM, HDIM, 0, 0, 0, 0, 0);
}

// Round 8
// 68.518 us; speedup vs baseline: 1.2371x; 1.1102x over previous
//
#include <hip/hip_runtime.h>
#include <math.h>

#define B_    2
#define S_    512
#define HDIM  1024
#define D_    24      // proj dim
#define M_    96      // pair-MLP hidden
#define ROWS  (B_*S_) // 1024

typedef _Float16 half8 __attribute__((ext_vector_type(8)));
typedef float    f32x4 __attribute__((ext_vector_type(4)));
typedef unsigned short ushort8 __attribute__((ext_vector_type(8)));

// ---------------------------------------------------------------------------
// cache-based 64x64 fp32->fp16 transpose (no LDS)
// ---------------------------------------------------------------------------
__device__ __forceinline__ void transpose_tile64_cache(
    const float* __restrict__ in, _Float16* __restrict__ out,
    int R, int C, int xt, int yt, int t) {
  int R0 = yt * 64, C0 = xt * 64;
  int c = t >> 2, rq = (t & 3) * 16;
  _Float16 o[16];
  const float* src = in + (size_t)(R0 + rq) * C + C0 + c;
#pragma unroll
  for (int e = 0; e < 16; ++e) o[e] = (_Float16)src[(size_t)e * C];
  _Float16* dst = out + (size_t)(C0 + c) * R + R0 + rq;
  *(ushort8*)dst = *(ushort8*)o;
  *(ushort8*)(dst + 8) = *(ushort8*)&o[8];
}

// ---------------------------------------------------------------------------
// MFMA projection, 64 rows per block (4 waves x 16 rows). P ([1024][24] fp32)
// is staged inline into LDS as fp16 B-fragments in two 16-step phases (32KB).
// B-frag slot s = step*128 + nt*64 + hi*16 + lo holds P[step*32+hi*8+e][nt*16+lo].
// A-frags: fp32 global loads + cvt (emits fp16 H image for Hj blocks).
// C layout: col = lane&15 (=d), row = (lane>>4)*4 + rg.
// ---------------------------------------------------------------------------
template <bool EMITH>
__device__ __forceinline__ void proj_mfma64(
    const float* __restrict__ H, const float* __restrict__ P,
    float* __restrict__ Z, _Float16* __restrict__ Himg,
    int r0, char* smem, int t) {
  const int w = t >> 6, l = t & 63;
  const int lo = l & 15, hi = l >> 4;
  const int row = r0 + w * 16 + lo;
  const float* hrow = H + (size_t)row * HDIM;
  f32x4 acc0 = {}, acc1 = {};

  for (int ph = 0; ph < 2; ++ph) {
    if (ph) __syncthreads();   // all waves done reading phase-0 fragments
    // stage 2048 fragment slots for steps [ph*16, ph*16+16)
    for (int q = 0; q < 8; ++q) {
      int s = t + q * 256;
      int slo = s & 15, shi = (s >> 4) & 3, snt = (s >> 6) & 1, sst = s >> 7;
      int d = snt * 16 + slo;
      half8 v = {};
      if (d < D_) {
        int k = (ph * 16 + sst) * 32 + shi * 8;
#pragma unroll
        for (int e = 0; e < 8; ++e)
          v[e] = (_Float16)P[(size_t)(k + e) * D_ + d];
      }
      *(half8*)(smem + s * 16) = v;
    }
    __syncthreads();

    for (int st = 0; st < 16; ++st) {
      int step = ph * 16 + st;
      const float* src = hrow + step * 32 + hi * 8;
      float4 v0 = *(const float4*)src;
      float4 v1 = *(const float4*)(src + 4);
      half8 a8;
      a8[0] = (_Float16)v0.x; a8[1] = (_Float16)v0.y;
      a8[2] = (_Float16)v0.z; a8[3] = (_Float16)v0.w;
      a8[4] = (_Float16)v1.x; a8[5] = (_Float16)v1.y;
      a8[6] = (_Float16)v1.z; a8[7] = (_Float16)v1.w;
      if (EMITH)
        *(half8*)(Himg + (size_t)row * HDIM + step * 32 + hi * 8) = a8;
      half8 b0 = *(const half8*)(smem + ((st * 2 + 0) * 64 + l) * 16);
      half8 b1 = *(const half8*)(smem + ((st * 2 + 1) * 64 + l) * 16);
      acc0 = __builtin_amdgcn_mfma_f32_16x16x32_f16(a8, b0, acc0, 0, 0, 0);
      acc1 = __builtin_amdgcn_mfma_f32_16x16x32_f16(a8, b1, acc1, 0, 0, 0);
    }
  }
#pragma unroll
  for (int rg = 0; rg < 4; ++rg) {
    int zr = r0 + w * 16 + hi * 4 + rg;
    Z[(size_t)zr * D_ + lo] = acc0[rg];
    if (lo < 8) Z[(size_t)zr * D_ + 16 + lo] = acc1[rg];
  }
}

// ---------------------------------------------------------------------------
// Merged prep kernel: blockIdx ranges
//  [0,16)      : proj Zj (+ HjH emit), 64 rows per block
//  [16,32)     : proj Zi, 64 rows per block
//  [32,36)     : Wimg (fp16 subtiled image of W1 rows 24..95 + zero pad)
//  [36,292)    : HiT 64x64 tiles (128 per batch)
//  [292,804)   : Wv1T tiles
//  [804,1060)  : Wv2T tiles
// ---------------------------------------------------------------------------
__global__ __launch_bounds__(256) void prep_kernel(
    const float* __restrict__ Hj, const float* __restrict__ Hi,
    const float* __restrict__ pj, const float* __restrict__ pi,
    const float* __restrict__ W1, const float* __restrict__ Wv1,
    const float* __restrict__ Wv2,
    _Float16* __restrict__ HjH, _Float16* __restrict__ HiT,
    _Float16* __restrict__ Wv1T, _Float16* __restrict__ Wv2T,
    _Float16* __restrict__ Wimg, float* __restrict__ Zj,
    float* __restrict__ Zi) {
  __shared__ __attribute__((aligned(16))) char smem[32768];
  const int bid = blockIdx.x;
  const int t = threadIdx.x;

  if (bid < 16) {
    proj_mfma64<true>(Hj, pj, Zj, HjH, bid * 64, smem, t);
  } else if (bid < 32) {
    proj_mfma64<false>(Hi, pi, Zi, nullptr, (bid - 16) * 64, smem, t);
  } else if (bid < 36) {
    int c = (bid - 32) * 256 + t;   // 0..1023
    half8 v = {};
    if (c < 864) {
      int kc = c / 96, m = c - kc * 96;
#pragma unroll
      for (int e = 0; e < 8; ++e)
        v[e] = (_Float16)W1[(24 + kc * 8 + e) * M_ + m];
    }
    *(half8*)(Wimg + (size_t)c * 8) = v;
  } else if (bid < 292) {
    int id = bid - 36;
    int z = id >> 7, rem = id & 127;   // 16 x 8 tiles per batch
    transpose_tile64_cache(Hi + (size_t)z * S_ * HDIM,
                           HiT + (size_t)z * HDIM * S_,
                           S_, HDIM, rem & 15, rem >> 4, t);
  } else if (bid < 804) {
    int id = bid - 292;                // 16 x 32 tiles
    transpose_tile64_cache(Wv1, Wv1T, 2 * HDIM, HDIM, id & 15, id >> 4, t);
  } else {
    int id = bid - 804;                // 16 x 16 tiles
    transpose_tile64_cache(Wv2, Wv2T, HDIM, HDIM, id & 15, id >> 4, t);
  }
}

// ---------------------------------------------------------------------------
// Fused pair-MLP + softmax. One block per j-row (1024 blocks, 256 thr).
// C = Wbig(M=96h) x F(N=keys): relu.W2 reduce = 24 in-lane FMAs + 2 shfl.
// ---------------------------------------------------------------------------
#define FOFFB   0                       // 10*256*16 = 40960
#define WOFFB   40960                   // 1024 chunks * 16 = 16384
#define ZOFFB   (WOFFB + 960*16)        // zero chunk
#define LOGOFFB (WOFFB + 16384)         // 512 f32 logits
#define ZJOFFB  (LOGOFFB + 2048)        // 24 f32
#define W2OFFB  (ZJOFFB + 96)           // 96 f32
#define REDOFFB (W2OFFB + 384)          // 8 f32
#define LDSB    (REDOFFB + 32)

__global__ __launch_bounds__(256) void pair_fused_kernel(
    const float* __restrict__ Zj, const float* __restrict__ Zi,
    const float* __restrict__ W1, const float* __restrict__ b1,
    const float* __restrict__ W2, const _Float16* __restrict__ Wimg,
    const float* __restrict__ mask, _Float16* __restrict__ probs) {
  __shared__ __attribute__((aligned(16))) char smem[LDSB];
  const int t = threadIdx.x;
  const int w = t >> 6, l = t & 63;
  const int lo = l & 15, hi = l >> 4;
  const int rj = blockIdx.x;
  const int b = rj >> 9;

  // stage weight image -> LDS (wave-linear dest)
#pragma unroll
  for (int r = 0; r < 4; ++r) {
    const _Float16* src = Wimg + (size_t)(r * 256 + w * 64 + l) * 8;
    __builtin_amdgcn_global_load_lds(
        (const __attribute__((address_space(1))) void*)src,
        (__attribute__((address_space(3))) void*)(smem + WOFFB + (r * 256 + w * 64) * 16),
        16, 0, 0);
  }
  float* zjL    = (float*)(smem + ZJOFFB);
  float* W2s    = (float*)(smem + W2OFFB);
  float* logits = (float*)(smem + LOGOFFB);
  float* red    = (float*)(smem + REDOFFB);
  if (t < D_) zjL[t] = Zj[(size_t)rj * D_ + t];
  if (t < M_) W2s[t] = W2[t];
  float aj = 0.f;
  if (t < M_) {
    aj = b1[t];
#pragma unroll
    for (int d = 0; d < D_; ++d)
      aj = fmaf(Zj[(size_t)rj * D_ + d], W1[d * M_ + t], aj);
  }
  __syncthreads();   // staging + zjL/W2s visible
  if (t < M_) {
    half8 v = {};
    v[0] = (_Float16)aj;
    *(half8*)(smem + WOFFB + (864 + t) * 16) = v;  // Aj row at K=72
  }

  half8 wf[6][3];
  float w2r[6][4];

  for (int p = 0; p < 2; ++p) {
    // ---- feature build: thread owns key i = p*256 + t ----
    {
      int i = p * 256 + t;
      const float* zi = Zi + (size_t)(b * S_ + i) * D_;
      float ziv[D_];
#pragma unroll
      for (int q = 0; q < 6; ++q) {
        float4 v = ((const float4*)zi)[q];
        ziv[q * 4 + 0] = v.x; ziv[q * 4 + 1] = v.y;
        ziv[q * 4 + 2] = v.z; ziv[q * 4 + 3] = v.w;
      }
#pragma unroll
      for (int kc = 0; kc < 3; ++kc) {
        half8 v;
#pragma unroll
        for (int e = 0; e < 8; ++e) v[e] = (_Float16)ziv[kc * 8 + e];
        *(half8*)(smem + FOFFB + (kc * 256 + t) * 16) = v;
      }
#pragma unroll
      for (int kc = 0; kc < 3; ++kc) {
        half8 v;
#pragma unroll
        for (int e = 0; e < 8; ++e) {
          int d = kc * 8 + e;
          v[e] = (_Float16)(zjL[d] * ziv[d]);
        }
        *(half8*)(smem + FOFFB + ((kc + 3) * 256 + t) * 16) = v;
      }
#pragma unroll
      for (int kc = 0; kc < 3; ++kc) {
        half8 v;
#pragma unroll
        for (int e = 0; e < 8; ++e) {
          int d = kc * 8 + e;
          v[e] = (_Float16)fabsf(zjL[d] - ziv[d]);
        }
        *(half8*)(smem + FOFFB + ((kc + 6) * 256 + t) * 16) = v;
      }
      if (p == 0) {
        half8 v = {};
        v[0] = (_Float16)1.0f;
        *(half8*)(smem + FOFFB + (9 * 256 + t) * 16) = v;
      }
    }
    __syncthreads();

    if (p == 0) {   // cache W fragments + W2 slice in regs (const across passes)
#pragma unroll
      for (int mh = 0; mh < 6; ++mh) {
#pragma unroll
        for (int ks = 0; ks < 3; ++ks) {
          int kc = ks * 4 + hi;
          int off = (kc < 10) ? (WOFFB + (kc * 96 + mh * 16 + lo) * 16) : ZOFFB;
          wf[mh][ks] = *(const half8*)(smem + off);
        }
#pragma unroll
        for (int r = 0; r < 4; ++r) w2r[mh][r] = W2s[mh * 16 + hi * 4 + r];
      }
    }

    // ---- MFMA: wave w owns keys w*64 .. w*64+63 (4 N-tiles) ----
#pragma unroll
    for (int nt = 0; nt < 4; ++nt) {
      half8 ff[3];
#pragma unroll
      for (int ks = 0; ks < 3; ++ks) {
        int kc = ks * 4 + hi;
        int off = (kc < 10) ? (FOFFB + (kc * 256 + w * 64 + nt * 16 + lo) * 16) : ZOFFB;
        ff[ks] = *(const half8*)(smem + off);
      }
      f32x4 a6[6] = {};
      __builtin_amdgcn_s_setprio(1);
#pragma unroll
      for (int ks = 0; ks < 3; ++ks)
#pragma unroll
        for (int mh = 0; mh < 6; ++mh)
          a6[mh] = __builtin_amdgcn_mfma_f32_16x16x32_f16(wf[mh][ks], ff[ks], a6[mh], 0, 0, 0);
      __builtin_amdgcn_s_setprio(0);
      float part = 0.f;
#pragma unroll
      for (int mh = 0; mh < 6; ++mh)
#pragma unroll
        for (int r = 0; r < 4; ++r)
          part = fmaf(fmaxf(a6[mh][r], 0.f), w2r[mh][r], part);
      part += __shfl_xor(part, 16);
      part += __shfl_xor(part, 32);
      if (hi == 0) logits[p * 256 + w * 64 + nt * 16 + lo] = part;
    }
    __syncthreads();
  }

  // ---- masked softmax over 512 keys (b2 dropped: shift-invariant) ----
  float m1 = mask[b * S_ + t], m2 = mask[b * S_ + t + 256];
  float lg1 = logits[t]       + (1.0f - m1) * (-3.40282347e38f);
  float lg2 = logits[t + 256] + (1.0f - m2) * (-3.40282347e38f);
  float mx = fmaxf(lg1, lg2);
#pragma unroll
  for (int off = 32; off > 0; off >>= 1) mx = fmaxf(mx, __shfl_xor(mx, off));
  if (l == 0) red[w] = mx;
  __syncthreads();
  float rmax = fmaxf(fmaxf(red[0], red[1]), fmaxf(red[2], red[3]));
  float e1 = __expf(lg1 - rmax);
  float e2 = __expf(lg2 - rmax);
  float s = e1 + e2;
#pragma unroll
  for (int off = 32; off > 0; off >>= 1) s += __shfl_xor(s, off);
  if (l == 0) red[4 + w] = s;
  __syncthreads();
  float inv = 1.0f / (red[4] + red[5] + red[6] + red[7]);
  probs[(size_t)rj * S_ + t]       = (_Float16)(e1 * inv);
  probs[(size_t)rj * S_ + t + 256] = (_Float16)(e2 * inv);
}

// ---------------------------------------------------------------------------
// fp16 MFMA GEMM, in-block split-K/2: 512 thr = 2 groups x 4 waves.
// (proven round-4 configuration)
// ---------------------------------------------------------------------------
template <bool HASA1, bool RELU, bool FINAL, bool OUTH>
__global__ __launch_bounds__(512) void mfma_gemm_kernel(
    const _Float16* __restrict__ A0, const _Float16* __restrict__ A1,
    const _Float16* __restrict__ Bt, const float* __restrict__ bias,
    const float* __restrict__ alpha_ptr, void* __restrict__ Cout,
    int M, int N, int K0, int K1,
    long aB0, long aB1, long bB, long cB) {
  __shared__ __attribute__((aligned(16))) char smem[65536];
  const int t = threadIdx.x;
  const int w = t >> 6, l = t & 63;
  const int g = w >> 2, wq = w & 3;
  const int K = K0 + K1;
  const int KH = K >> 1;
  const int NT = KH >> 5;
  const int n0 = blockIdx.x * 64, m0 = blockIdx.y * 64;
  const int zb = blockIdx.z;
  const _Float16* A0b = A0 + (size_t)zb * aB0;
  const _Float16* A1b = HASA1 ? (A1 + (size_t)zb * aB1) : nullptr;
  const _Float16* Btb = Bt + (size_t)zb * bB;
  char* gls = smem + (g << 15);

  const int sr = (wq << 4) + (l >> 2);
  const int sk = ((l & 3) ^ ((l >> 3) & 3)) << 3;

  const int mq = wq >> 1, nq = wq & 1;
  int offA[2], offB[2];
#pragma unroll
  for (int i = 0; i < 2; ++i) {
    int ra = mq * 32 + i * 16 + (l & 15);
    offA[i] = ra * 64 + (((l >> 4) ^ ((ra >> 1) & 3)) << 4);
    int rb = nq * 32 + i * 16 + (l & 15);
    offB[i] = 4096 + rb * 64 + (((l >> 4) ^ ((rb >> 1) & 3)) << 4);
  }

  f32x4 acc[2][2] = {};

  auto stage = [&](int tt) {
    char* buf = gls + (tt & 3) * 8192;
    int kg = g * KH + (tt << 5) + sk;
    const _Float16* ga;
    if (HASA1 && kg >= K0) ga = A1b + (size_t)(m0 + sr) * K1 + (kg - K0);
    else                   ga = A0b + (size_t)(m0 + sr) * K0 + kg;
    __builtin_amdgcn_global_load_lds(
        (const __attribute__((address_space(1))) void*)ga,
        (__attribute__((address_space(3))) void*)(buf + (wq << 10)), 16, 0, 0);
    const _Float16* gb = Btb + (size_t)(n0 + sr) * K + kg;
    __builtin_amdgcn_global_load_lds(
        (const __attribute__((address_space(1))) void*)gb,
        (__attribute__((address_space(3))) void*)(buf + 4096 + (wq << 10)), 16, 0, 0);
  };

  stage(0);
  stage(1);
  stage(2);

  for (int tt = 0; tt < NT; ++tt) {
    if (tt + 2 < NT)      asm volatile("s_waitcnt vmcnt(4)" ::: "memory");
    else if (tt + 1 < NT) asm volatile("s_waitcnt vmcnt(2)" ::: "memory");
    else                  asm volatile("s_waitcnt vmcnt(0)" ::: "memory");
    __builtin_amdgcn_s_barrier();
    __builtin_amdgcn_sched_barrier(0);
    const char* buf = gls + (tt & 3) * 8192;
    half8 a0 = *(const half8*)(buf + offA[0]);
    half8 a1 = *(const half8*)(buf + offA[1]);
    half8 b0 = *(const half8*)(buf + offB[0]);
    half8 b1v = *(const half8*)(buf + offB[1]);
    acc[0][0] = __builtin_amdgcn_mfma_f32_16x16x32_f16(a0, b0, acc[0][0], 0, 0, 0);
    acc[0][1] = __builtin_amdgcn_mfma_f32_16x16x32_f16(a0, b1v, acc[0][1], 0, 0, 0);
    acc[1][0] = __builtin_amdgcn_mfma_f32_16x16x32_f16(a1, b0, acc[1][0], 0, 0, 0);
    acc[1][1] = __builtin_amdgcn_mfma_f32_16x16x32_f16(a1, b1v, acc[1][1], 0, 0, 0);
    if (tt + 3 < NT) stage(tt + 3);
  }

  // cross-group K reduction through LDS (overlays group-0 ring, now dead)
  const int lr = l & 15, lq = l >> 4;
  float* redm = (float*)smem;   // [64][68]
  __syncthreads();
  if (g == 1) {
#pragma unroll
    for (int mi = 0; mi < 2; ++mi)
#pragma unroll
      for (int ni = 0; ni < 2; ++ni)
#pragma unroll
        for (int rg = 0; rg < 4; ++rg)
          redm[(mq * 32 + mi * 16 + lq * 4 + rg) * 68 + nq * 32 + ni * 16 + lr] =
              acc[mi][ni][rg];
  }
  __syncthreads();
  if (g == 0) {
    const float alpha = FINAL ? *alpha_ptr : 1.0f;
    const size_t cbase = (size_t)zb * cB;
#pragma unroll
    for (int mi = 0; mi < 2; ++mi)
#pragma unroll
      for (int ni = 0; ni < 2; ++ni) {
        int col = n0 + nq * 32 + ni * 16 + lr;
        float bv = bias ? bias[col] : 0.0f;
#pragma unroll
        for (int rg = 0; rg < 4; ++rg) {
          int row = m0 + mq * 32 + mi * 16 + lq * 4 + rg;
          float x = acc[mi][ni][rg] +
                    redm[(mq * 32 + mi * 16 + lq * 4 + rg) * 68 + nq * 32 + ni * 16 + lr] +
                    bv;
          if (RELU) x = fmaxf(x, 0.f);
          if (FINAL) x *= alpha;
          if (OUTH)
            ((_Float16*)Cout)[cbase + (size_t)row * N + col] = (_Float16)x;
          else
            ((float*)Cout)[cbase + (size_t)row * N + col] = x;
        }
      }
  }
}

// ---------------------------------------------------------------------------
extern "C" void kernel_launch(void* const* d_in, const int* in_sizes, int n_in,
                              void* d_out, int out_size, void* d_ws, size_t ws_size,
                              hipStream_t stream) {
  const float* Hj   = (const float*)d_in[0];
  const float* Hi   = (const float*)d_in[1];
  const float* mask = (const float*)d_in[2];
  const float* pj   = (const float*)d_in[3];
  const float* pi   = (const float*)d_in[4];
  const float* W1   = (const float*)d_in[5];
  const float* b1   = (const float*)d_in[6];
  const float* W2   = (const float*)d_in[7];
  // d_in[8] = b2: uniform over keys -> softmax invariant, unused
  const float* Wv1  = (const float*)d_in[9];
  const float* bv1  = (const float*)d_in[10];
  const float* Wv2  = (const float*)d_in[11];
  const float* bv2  = (const float*)d_in[12];
  const float* alpha = (const float*)d_in[13];

  char* w = (char*)d_ws;
  float* Zj  = (float*)w;            w += (size_t)ROWS * D_ * 4;
  float* Zi  = (float*)w;            w += (size_t)ROWS * D_ * 4;
  _Float16* Wimg   = (_Float16*)w;   w += (size_t)1024 * 16;
  _Float16* probsH = (_Float16*)w;   w += (size_t)B_ * S_ * S_ * 2;
  _Float16* HjH    = (_Float16*)w;   w += (size_t)ROWS * HDIM * 2;
  _Float16* HiT    = (_Float16*)w;   w += (size_t)B_ * HDIM * S_ * 2;
  _Float16* Wv1T   = (_Float16*)w;   w += (size_t)HDIM * 2 * HDIM * 2;
  _Float16* Wv2T   = (_Float16*)w;   w += (size_t)HDIM * HDIM * 2;
  _Float16* ctxH   = (_Float16*)w;   w += (size_t)ROWS * HDIM * 2;
  _Float16* hidH   = (_Float16*)w;   w += (size_t)ROWS * HDIM * 2;
  float* out = (float*)d_out;

  // all prep: projections (MFMA, inline P staging), weight images, transposes
  prep_kernel<<<1060, 256, 0, stream>>>(Hj, Hi, pj, pi, W1, Wv1, Wv2,
                                        HjH, HiT, Wv1T, Wv2T, Wimg, Zj, Zi);

  pair_fused_kernel<<<ROWS, 256, 0, stream>>>(Zj, Zi, W1, b1, W2, Wimg,
                                              mask, probsH);

  // ctx[b] = probs[b] @ Hi[b]   (M=512, N=1024, K=512) -> fp16
  mfma_gemm_kernel<false, false, false, true><<<dim3(16, 8, 2), 512, 0, stream>>>(
      probsH, nullptr, HiT, nullptr, nullptr, ctxH,
      S_, HDIM, S_, 0, (long)S_ * S_, 0, (long)HDIM * S_, (long)S_ * HDIM);
  // hidden = relu([ctx | Hj] @ Wv1 + bv1)   (M=1024, N=1024, K=2048) -> fp16
  mfma_gemm_kernel<true, true, false, true><<<dim3(16, 16, 1), 512, 0, stream>>>(
      ctxH, HjH, Wv1T, bv1, nullptr, hidH,
      ROWS, HDIM, HDIM, HDIM, 0, 0, 0, 0);
  // out = alpha * (hidden @ Wv2 + bv2)      (M=1024, N=1024, K=1024) -> fp32
  mfma_gemm_kernel<false, false, true, false><<<dim3(16, 16, 1), 512, 0, stream>>>(
      hidH, nullptr, Wv2T, bv2, alpha, out,
      ROWS, HDIM, HDIM, 0, 0, 0, 0, 0);
}